// Round 6
// baseline (239.883 us; speedup 1.0000x reference)
//
#include <hip/hip_runtime.h>
#include <math.h>

// Problem constants
#define NN 8
#define C_TOTAL 448
#define CC 100
#define HH 56
#define WW 56
#define HW (HH*WW)          // 3136
#define NPIX4 (HW/4)        // 784 quads (float4 pixel groups)
#define OH 224
#define OW 224
#define NPAIR 50            // row pairs (r, 99-r): 101 cov columns each
#define NT4 13              // ceil(784/64) quad tiles
#define NCHUNK 13           // ceil(101/8) column chunks of 8

typedef __attribute__((ext_vector_type(4))) _Float16 half4;

__device__ __forceinline__ void fma4(float4& acc, const float4 a, const float4 b) {
    acc.x = fmaf(a.x, b.x, acc.x);
    acc.y = fmaf(a.y, b.y, acc.y);
    acc.z = fmaf(a.z, b.z, acc.z);
    acc.w = fmaf(a.w, b.w, acc.w);
}
__device__ __forceinline__ float4 h2f(const half4 h) {
    float4 r; r.x = (float)h.x; r.y = (float)h.y; r.z = (float)h.z; r.w = (float)h.w;
    return r;
}

// async global->LDS, 16 bytes per lane (global_load_lds_dwordx4)
__device__ __forceinline__ void gload16(const void* g, void* l) {
    __builtin_amdgcn_global_load_lds(
        (const __attribute__((address_space(1))) unsigned int*)g,
        (__attribute__((address_space(3))) unsigned int*)l, 16, 0, 0);
}

// ---------------------------------------------------------------------------
// Kernel 0: x[n,c,quad] = fmaps[n, sel[c], quad] - mean[c, quad]  -> fp16
// ---------------------------------------------------------------------------
__global__ __launch_bounds__(256) void prep_x_kernel(
    const float* __restrict__ fmaps, const int* __restrict__ sel,
    const float* __restrict__ mean, half4* __restrict__ xbuf)
{
    const int idx = blockIdx.x * 256 + threadIdx.x;
    const int total = NN * CC * NPIX4;
    if (idx >= total) return;
    const int p4 = idx % NPIX4;
    const int c  = (idx / NPIX4) % CC;
    const int n  = idx / (NPIX4 * CC);

    const float4* f4 = (const float4*)fmaps;
    const float4* m4 = (const float4*)mean;

    const float4 f = f4[((size_t)n * C_TOTAL + sel[c]) * NPIX4 + p4];
    const float4 m = m4[(size_t)c * NPIX4 + p4];
    half4 r;
    r.x = (_Float16)(f.x - m.x);
    r.y = (_Float16)(f.y - m.y);
    r.z = (_Float16)(f.z - m.z);
    r.w = (_Float16)(f.w - m.w);
    xbuf[((size_t)n * CC + c) * NPIX4 + p4] = r;
}

// ---------------------------------------------------------------------------
// Kernel 1: pair (r, s=99-r) symmetric quadratic form with async LDS staging.
// Block = (pair, quad-tile of 64), 512 threads = 8 waves.
//   Staging: chunk k = cov columns c = 8k..8k+7 of the pair's 101-column list
//            (col c<=99-r -> row r, d=r+c;  else row s, d=s+(c-(100-r))).
//            Wave w stages column 8k+w: lane's 16 B via global_load_lds.
//   Compute: wave n processes its image: for each staged column,
//            acc(row) += wgt * x[n,d,quad] * cov_col   (wgt=0.5 on diagonals)
//   Final:   qpart[r][n][quad] = 2*(x_r*accR + x_s*accS);  sum over pairs
//            == x^T cov x  (cov bitwise symmetric).
// ---------------------------------------------------------------------------
__global__ __launch_bounds__(512) void qform_kernel(
    const half4* __restrict__ xbuf, const float* __restrict__ cov,
    float* __restrict__ qpart)
{
    __shared__ float4 sbuf[2][8][64];   // 2 bufs x 8 cols x 64 quads = 16 KB

    const int tile = blockIdx.x % NT4;
    const int r    = blockIdx.x / NT4;      // 0..49
    const int s    = CC - 1 - r;            // 99-r
    const int w    = threadIdx.x >> 6;      // wave id 0..7
    const int lane = threadIdx.x & 63;
    const int qraw = tile * 64 + lane;
    const bool valid = qraw < NPIX4;
    const int quad = valid ? qraw : (NPIX4 - 1);   // clamp, no early return

    const int splitc = 100 - r;             // first column index of row s

    // ---- staging lambda: issue this thread's 16 B of chunk k into buf b ----
    auto stage = [&](int k, int b) {
        int c = k * 8 + w;
        if (c > 100) c = 100;               // clamp (last chunk partial)
        const bool inR = (c < splitc);
        const int row = inR ? r : s;
        const int d   = inR ? (r + c) : (s + (c - splitc));
        const float4* src = (const float4*)cov + ((size_t)row * CC + d) * NPIX4 + quad;
        gload16((const void*)src, (void*)&sbuf[b][w][lane]);
    };

    const half4* xn = xbuf + (size_t)w * CC * NPIX4;   // wave w == image n

    float4 accR = make_float4(0.f, 0.f, 0.f, 0.f);
    float4 accS = make_float4(0.f, 0.f, 0.f, 0.f);

    stage(0, 0);
    for (int k = 0; k < NCHUNK; ++k) {
        if (k + 1 < NCHUNK) stage(k + 1, (k + 1) & 1);
        __syncthreads();    // vmcnt drained: chunk k resident in sbuf[k&1]

        const int b = k & 1;
#pragma unroll
        for (int j = 0; j < 8; ++j) {
            const int c = k * 8 + j;
            if (c > 100) break;             // block-uniform
            const bool inR = (c < splitc);
            const int d = inR ? (r + c) : (s + (c - splitc));
            const float wgt = (c == 0 || c == splitc) ? 0.5f : 1.0f;

            const float4 cv = sbuf[b][j][lane];                    // ds_read_b128
            float4 xd = h2f(xn[(size_t)d * NPIX4 + quad]);         // 8 B, L2-hot
            xd.x *= wgt; xd.y *= wgt; xd.z *= wgt; xd.w *= wgt;
            if (inR) fma4(accR, xd, cv);
            else     fma4(accS, xd, cv);
        }
        __syncthreads();    // protect buffer reuse
    }

    if (valid) {
        const float4 xr = h2f(xn[(size_t)r * NPIX4 + quad]);
        const float4 xs = h2f(xn[(size_t)s * NPIX4 + quad]);
        float4 q;
        q.x = 2.0f * fmaf(xr.x, accR.x, xs.x * accS.x);
        q.y = 2.0f * fmaf(xr.y, accR.y, xs.y * accS.y);
        q.z = 2.0f * fmaf(xr.z, accR.z, xs.z * accS.z);
        q.w = 2.0f * fmaf(xr.w, accR.w, xs.w * accS.w);
        ((float4*)qpart)[((size_t)r * NN + w) * NPIX4 + qraw] = q;
    }
}

// ---------------------------------------------------------------------------
// Kernel 2: reduce partials over the 50 pairs, sqrt -> s_map (N,HW)
// ---------------------------------------------------------------------------
__global__ __launch_bounds__(256) void reduce_kernel(
    const float* __restrict__ qpart, float* __restrict__ smap)
{
    const int idx = blockIdx.x * 256 + threadIdx.x;   // over N*NPIX4
    if (idx >= NN * NPIX4) return;
    const int p4 = idx % NPIX4;
    const int n  = idx / NPIX4;

    const float4* qp = (const float4*)qpart;
    float4 acc = make_float4(0.f, 0.f, 0.f, 0.f);
#pragma unroll
    for (int k = 0; k < NPAIR; ++k) {
        const float4 v = qp[((size_t)k * NN + n) * NPIX4 + p4];
        acc.x += v.x; acc.y += v.y; acc.z += v.z; acc.w += v.w;
    }
    float4 o;
    o.x = sqrtf(fmaxf(acc.x, 0.f));
    o.y = sqrtf(fmaxf(acc.y, 0.f));
    o.z = sqrtf(fmaxf(acc.z, 0.f));
    o.w = sqrtf(fmaxf(acc.w, 0.f));
    ((float4*)smap)[(size_t)n * NPIX4 + p4] = o;
}

// ---------------------------------------------------------------------------
// Kernel 3: bilinear x4 upsample (half-pixel, edge clamp) + normalize
// ---------------------------------------------------------------------------
__global__ __launch_bounds__(256) void upsample_kernel(
    const float* __restrict__ smap,
    const float* __restrict__ minp, const float* __restrict__ maxp,
    float* __restrict__ out)
{
    const int idx = blockIdx.x * 256 + threadIdx.x;
    const int total = NN * OH * OW;
    if (idx >= total) return;

    const int ox = idx % OW;
    const int oy = (idx / OW) % OH;
    const int n  = idx / (OW * OH);

    const float fy = oy * 0.25f - 0.375f;
    const float fx = ox * 0.25f - 0.375f;

    int y0 = (int)floorf(fy);
    int x0 = (int)floorf(fx);
    const float wy = fy - (float)y0;
    const float wx = fx - (float)x0;
    int y1 = min(y0 + 1, HH - 1); y0 = max(y0, 0);
    int x1 = min(x0 + 1, WW - 1); x0 = max(x0, 0);

    const float* sm = smap + (size_t)n * HW;
    const float v00 = sm[y0 * WW + x0];
    const float v01 = sm[y0 * WW + x1];
    const float v10 = sm[y1 * WW + x0];
    const float v11 = sm[y1 * WW + x1];

    const float v = (1.0f - wy) * ((1.0f - wx) * v00 + wx * v01)
                  +          wy * ((1.0f - wx) * v10 + wx * v11);

    const float mn = *minp;
    const float mx = *maxp;
    out[idx] = (v - mn) / (mx - mn);
}

// ---------------------------------------------------------------------------
extern "C" void kernel_launch(void* const* d_in, const int* in_sizes, int n_in,
                              void* d_out, int out_size, void* d_ws, size_t ws_size,
                              hipStream_t stream)
{
    const float* fmaps = (const float*)d_in[0];
    const int*   sel   = (const int*)  d_in[1];
    const float* mean  = (const float*)d_in[2];
    const float* cov   = (const float*)d_in[3];
    const float* minp  = (const float*)d_in[4];
    const float* maxp  = (const float*)d_in[5];
    float* out = (float*)d_out;

    half4* xbuf  = (half4*)d_ws;                                  // NN*CC*NPIX4 half4 = 5.0 MB
    float* qpart = (float*)((char*)d_ws + (size_t)NN*CC*NPIX4*8); // NPAIR*NN*HW f32 = 5.0 MB
    float* smap  = qpart + (size_t)NPAIR * NN * HW;               // NN*HW f32 = 0.1 MB

    {
        const int total = NN * CC * NPIX4;
        prep_x_kernel<<<(total + 255) / 256, 256, 0, stream>>>(fmaps, sel, mean, xbuf);
    }
    qform_kernel<<<NT4 * NPAIR, 512, 0, stream>>>(xbuf, cov, qpart);
    {
        const int total = NN * NPIX4;
        reduce_kernel<<<(total + 255) / 256, 256, 0, stream>>>(qpart, smap);
    }
    {
        const int total = NN * OH * OW;
        upsample_kernel<<<(total + 255) / 256, 256, 0, stream>>>(smap, minp, maxp, out);
    }
}